// Round 6
// baseline (279.871 us; speedup 1.0000x reference)
//
#include <hip/hip_runtime.h>
#include <hip/hip_bf16.h>

// IntraCellularAttention: B=1024, D_INNER=4096, D_STATE=16, D_ATTN=16
// out[b,d,s] = h[b,d,s] + gate * sum_t attn[b,s,t] * h[b,d,t]
// attn[s,t] = softmax_t( (Q K^T)[s,t] * 0.25 ),  Q[s,a] = sum_d h[b,d,s] Wq[a,d]
//
// Single fused kernel, 512 threads (8 waves), 1 block/batch, grid 1024.
// 4 blocks/CU x 8 waves = 32 waves/CU (100% occupancy) -- needs VGPR<=64
// (launch_bounds(512,8)) and LDS <= 40KB/block (~21.5KB used).
//   Phase 1: Q,K via mfma_16x16x32_bf16, wave wv covers 512 d-rows,
//            2-slot pipeline; partials reduced through LDS.
//   Phase 2: softmax on 256 threads, fold gate into Ms (PV-only, no identity).
//   Phase 3: PV via MFMA with hoisted B-frag (Ms, K=16 zero-padded to 32),
//            residual added in fp32 from separate dword loads (exactness),
//            1-tile prefetch, non-temporal stores.

constexpr int DI = 4096;
constexpr int DS = 16;
constexpr int NW = 8;                       // waves per block

typedef __attribute__((ext_vector_type(8))) short bf16x8;
typedef __attribute__((ext_vector_type(4))) float f32x4;

static __device__ __forceinline__ short f2bf(float x) {
    union { __hip_bfloat16 h; short s; } u;
    u.h = __float2bfloat16(x);
    return u.s;
}

__global__ __launch_bounds__(512, 8) void ica_fused(
    const float* __restrict__ h,
    const float* __restrict__ Wq,
    const float* __restrict__ Wk,
    const float* __restrict__ gate,
    float* __restrict__ out)
{
    const int b    = blockIdx.x;
    const int tid  = threadIdx.x;
    const int lane = tid & 63;
    const int wv   = tid >> 6;              // 0..7

    const float* __restrict__ hbase = h   + (size_t)b * (DI * DS);
    float*       __restrict__ obase = out + (size_t)b * (DI * DS);

    __shared__ float qp[NW][16][17];        // per-wave Q partials [w][s][a]
    __shared__ float kp[NW][16][17];
    __shared__ float Qs[16][20];            // reduced Q [s][a]
    __shared__ float Ks[16][20];
    __shared__ float Ms[16][20];            // Ms[s][t] = g * attn[s][t]

    const int sa = lane & 15;               // A row (s) / B row (a) / col
    const int kb = lane >> 4;               // k-subblock 0..3

    // ---------------- Phase 1: Q,K partials via MFMA, 2-slot pipeline -----
    {
        constexpr int ROWS = DI / NW;       // 512 d-rows per wave
        constexpr int NIT  = ROWS / 32;     // 16 K-iterations
        const int d0w = wv * ROWS;
        const float* __restrict__ wqb = Wq + (size_t)sa * DI;
        const float* __restrict__ wkb = Wk + (size_t)sa * DI;

        f32x4 accQ = {0.f, 0.f, 0.f, 0.f};
        f32x4 accK = {0.f, 0.f, 0.f, 0.f};

#define P1_LD(IT, A, Q0, Q1, K0, K1) do {                                   \
        const int db_ = d0w + (IT) * 32 + kb * 8;                           \
        const float* __restrict__ hp_ = hbase + (size_t)db_ * DS + sa;      \
        A[0] = hp_[0 * DS]; A[1] = hp_[1 * DS];                             \
        A[2] = hp_[2 * DS]; A[3] = hp_[3 * DS];                             \
        A[4] = hp_[4 * DS]; A[5] = hp_[5 * DS];                             \
        A[6] = hp_[6 * DS]; A[7] = hp_[7 * DS];                             \
        Q0 = *(const float4*)(wqb + db_); Q1 = *(const float4*)(wqb + db_ + 4); \
        K0 = *(const float4*)(wkb + db_); K1 = *(const float4*)(wkb + db_ + 4); \
    } while (0)

#define P1_FMA(A, Q0, Q1, K0, K1) do {                                      \
        bf16x8 af_, bq_, bk_;                                               \
        af_[0] = f2bf(A[0]); af_[1] = f2bf(A[1]);                           \
        af_[2] = f2bf(A[2]); af_[3] = f2bf(A[3]);                           \
        af_[4] = f2bf(A[4]); af_[5] = f2bf(A[5]);                           \
        af_[6] = f2bf(A[6]); af_[7] = f2bf(A[7]);                           \
        bq_[0] = f2bf(Q0.x); bq_[1] = f2bf(Q0.y);                           \
        bq_[2] = f2bf(Q0.z); bq_[3] = f2bf(Q0.w);                           \
        bq_[4] = f2bf(Q1.x); bq_[5] = f2bf(Q1.y);                           \
        bq_[6] = f2bf(Q1.z); bq_[7] = f2bf(Q1.w);                           \
        bk_[0] = f2bf(K0.x); bk_[1] = f2bf(K0.y);                           \
        bk_[2] = f2bf(K0.z); bk_[3] = f2bf(K0.w);                           \
        bk_[4] = f2bf(K1.x); bk_[5] = f2bf(K1.y);                           \
        bk_[6] = f2bf(K1.z); bk_[7] = f2bf(K1.w);                           \
        accQ = __builtin_amdgcn_mfma_f32_16x16x32_bf16(af_, bq_, accQ, 0, 0, 0); \
        accK = __builtin_amdgcn_mfma_f32_16x16x32_bf16(af_, bk_, accK, 0, 0, 0); \
    } while (0)

        float A0[8], A1[8];
        float4 Q00, Q01, K00, K01;
        float4 Q10, Q11, K10, K11;
        P1_LD(0, A0, Q00, Q01, K00, K01);
        P1_LD(1, A1, Q10, Q11, K10, K11);
        for (int it = 0; it < NIT - 2; it += 2) {
            P1_FMA(A0, Q00, Q01, K00, K01);
            P1_LD(it + 2, A0, Q00, Q01, K00, K01);
            P1_FMA(A1, Q10, Q11, K10, K11);
            P1_LD(it + 3, A1, Q10, Q11, K10, K11);
        }
        P1_FMA(A0, Q00, Q01, K00, K01);
        P1_FMA(A1, Q10, Q11, K10, K11);
#undef P1_LD
#undef P1_FMA

        // D mapping (verified): col = lane&15 (=a), row = (lane>>4)*4+reg (=s)
        #pragma unroll
        for (int r = 0; r < 4; ++r) {
            qp[wv][kb * 4 + r][sa] = accQ[r];
            kp[wv][kb * 4 + r][sa] = accK[r];
        }
    }
    __syncthreads();

    // ---------------- reduce the 8 wave partials --------------------------
    {
        const int idx = tid & 255;
        const int s2 = idx >> 4, a2 = idx & 15;
        if (tid < 256) {
            float q = 0.f;
            #pragma unroll
            for (int w = 0; w < NW; ++w) q += qp[w][s2][a2];
            Qs[s2][a2] = q;
        } else {
            float k = 0.f;
            #pragma unroll
            for (int w = 0; w < NW; ++w) k += kp[w][s2][a2];
            Ks[s2][a2] = k;
        }
    }
    __syncthreads();

    // ---------------- Phase 2: scores + softmax + fold gate ---------------
    const float g = gate[0];
    if (tid < 256) {
        const int ss = tid >> 4;   // query slot
        const int tt = tid & 15;   // key slot
        float sc = 0.f;
        #pragma unroll
        for (int a4 = 0; a4 < 16; a4 += 4) {
            float4 qv = *(const float4*)&Qs[ss][a4];
            float4 kv = *(const float4*)&Ks[tt][a4];
            sc = fmaf(qv.x, kv.x, sc);
            sc = fmaf(qv.y, kv.y, sc);
            sc = fmaf(qv.z, kv.z, sc);
            sc = fmaf(qv.w, kv.w, sc);
        }
        sc *= 0.25f;  // D_ATTN^-0.5

        float m = sc;
        #pragma unroll
        for (int o = 8; o > 0; o >>= 1) m = fmaxf(m, __shfl_xor(m, o, 16));
        float e = __expf(sc - m);
        float sm = e;
        #pragma unroll
        for (int o = 8; o > 0; o >>= 1) sm += __shfl_xor(sm, o, 16);
        Ms[ss][tt] = g * (e / sm);
    }
    __syncthreads();

    // ---------------- Phase 3: PV via MFMA + fp32 residual ----------------
    {
        constexpr int ROWS = DI / NW;       // 512 rows per wave
        constexpr int NT3  = ROWS / 16;     // 32 tiles per wave
        const int rbase = wv * ROWS;
        const int c = sa;                   // output column (s)

        // hoisted B fragment: B[k=t][col=s] = Ms[s][t], zero for t>=16
        bf16x8 bfrag = {0, 0, 0, 0, 0, 0, 0, 0};
        if (kb < 2) {
            const float* mp = &Ms[c][kb * 8];
            float4 m0 = *(const float4*)mp;
            float4 m1 = *(const float4*)(mp + 4);
            bfrag[0] = f2bf(m0.x); bfrag[1] = f2bf(m0.y);
            bfrag[2] = f2bf(m0.z); bfrag[3] = f2bf(m0.w);
            bfrag[4] = f2bf(m1.x); bfrag[5] = f2bf(m1.y);
            bfrag[6] = f2bf(m1.z); bfrag[7] = f2bf(m1.w);
        }

        // prefetch slot: A-frag (kb<2) + residual (all lanes)
        float4 a0n = {0.f, 0.f, 0.f, 0.f}, a1n = {0.f, 0.f, 0.f, 0.f};
        float r0n, r1n, r2n, r3n;
        {
            if (kb < 2) {
                const float* hr = hbase + (size_t)(rbase + c) * DS + kb * 8;
                a0n = *(const float4*)hr;
                a1n = *(const float4*)(hr + 4);
            }
            const int rr = rbase + kb * 4;
            r0n = hbase[(size_t)(rr + 0) * DS + c];
            r1n = hbase[(size_t)(rr + 1) * DS + c];
            r2n = hbase[(size_t)(rr + 2) * DS + c];
            r3n = hbase[(size_t)(rr + 3) * DS + c];
        }

        for (int it = 0; it < NT3; ++it) {
            float4 a0 = a0n, a1 = a1n;
            float h0 = r0n, h1 = r1n, h2 = r2n, h3 = r3n;
            if (it + 1 < NT3) {
                const int rb2 = rbase + (it + 1) * 16;
                if (kb < 2) {
                    const float* hr = hbase + (size_t)(rb2 + c) * DS + kb * 8;
                    a0n = *(const float4*)hr;
                    a1n = *(const float4*)(hr + 4);
                }
                const int rr = rb2 + kb * 4;
                r0n = hbase[(size_t)(rr + 0) * DS + c];
                r1n = hbase[(size_t)(rr + 1) * DS + c];
                r2n = hbase[(size_t)(rr + 2) * DS + c];
                r3n = hbase[(size_t)(rr + 3) * DS + c];
            }

            bf16x8 af;
            af[0] = f2bf(a0.x); af[1] = f2bf(a0.y); af[2] = f2bf(a0.z); af[3] = f2bf(a0.w);
            af[4] = f2bf(a1.x); af[5] = f2bf(a1.y); af[6] = f2bf(a1.z); af[7] = f2bf(a1.w);

            f32x4 acc = {0.f, 0.f, 0.f, 0.f};
            acc = __builtin_amdgcn_mfma_f32_16x16x32_bf16(af, bfrag, acc, 0, 0, 0);

            const int rr = rbase + it * 16 + kb * 4;
            __builtin_nontemporal_store(h0 + acc[0], &obase[(size_t)(rr + 0) * DS + c]);
            __builtin_nontemporal_store(h1 + acc[1], &obase[(size_t)(rr + 1) * DS + c]);
            __builtin_nontemporal_store(h2 + acc[2], &obase[(size_t)(rr + 2) * DS + c]);
            __builtin_nontemporal_store(h3 + acc[3], &obase[(size_t)(rr + 3) * DS + c]);
        }
    }
}

extern "C" void kernel_launch(void* const* d_in, const int* in_sizes, int n_in,
                              void* d_out, int out_size, void* d_ws, size_t ws_size,
                              hipStream_t stream) {
    const float* h    = (const float*)d_in[0];
    const float* Wq   = (const float*)d_in[1];
    const float* Wk   = (const float*)d_in[2];
    const float* gate = (const float*)d_in[3];
    float* out = (float*)d_out;
    (void)in_sizes; (void)n_in; (void)out_size; (void)d_ws; (void)ws_size;

    ica_fused<<<1024, 512, 0, stream>>>(h, Wq, Wk, gate, out);
}

// Round 7
// 266.827 us; speedup vs baseline: 1.0489x; 1.0489x over previous
//
#include <hip/hip_runtime.h>
#include <hip/hip_bf16.h>

// IntraCellularAttention: B=1024, D_INNER=4096, D_STATE=16, D_ATTN=16
// out[b,d,s] = h[b,d,s] + gate * sum_t attn[b,s,t] * h[b,d,t]
// attn[s,t] = softmax_t( (Q K^T)[s,t] * 0.25 ),  Q[s,a] = sum_d h[b,d,s] Wq[a,d]
//
// Single fused kernel, 512 threads (8 waves), 1 block/batch, grid 1024.
// 4 blocks/CU x 8 waves = 32 waves/CU -- needs VGPR<=64, LDS<=40KB (~30KB).
//   Phase 1: Q,K via mfma_16x16x32_bf16, wave covers 512 d-rows, 2-slot pipe.
//   Phase 2: softmax on 256 threads, fold gate into Ms.
//   Phase 3: PV via MFMA (hoisted Ms B-frag, K=16 zero-padded), per-wave LDS
//            transpose of the D fragment -> row-major, fp32 residual added
//            from L1-hot float4 h re-read, float4 NT stores (full lines).

constexpr int DI = 4096;
constexpr int DS = 16;
constexpr int NW = 8;                       // waves per block

typedef __attribute__((ext_vector_type(8))) short bf16x8;
typedef __attribute__((ext_vector_type(4))) float f32x4;

static __device__ __forceinline__ short f2bf(float x) {
    union { __hip_bfloat16 h; short s; } u;
    u.h = __float2bfloat16(x);
    return u.s;
}

__global__ __launch_bounds__(512, 8) void ica_fused(
    const float* __restrict__ h,
    const float* __restrict__ Wq,
    const float* __restrict__ Wk,
    const float* __restrict__ gate,
    float* __restrict__ out)
{
    const int b    = blockIdx.x;
    const int tid  = threadIdx.x;
    const int lane = tid & 63;
    const int wv   = tid >> 6;              // 0..7

    const float* __restrict__ hbase = h   + (size_t)b * (DI * DS);
    float*       __restrict__ obase = out + (size_t)b * (DI * DS);

    __shared__ float qp[NW][16][17];        // per-wave Q partials [w][s][a]
    __shared__ float kp[NW][16][17];
    __shared__ float Qs[16][20];            // reduced Q [s][a]
    __shared__ float Ks[16][20];
    __shared__ float Ms[16][20];            // Ms[s][t] = g * attn[s][t]
    __shared__ float tr[NW][16][17];        // per-wave PV transpose tile

    const int sa = lane & 15;               // A row (s) / B row (a) / col
    const int kb = lane >> 4;               // k-subblock 0..3

    // ---------------- Phase 1: Q,K partials via MFMA, 2-slot pipeline -----
    {
        constexpr int ROWS = DI / NW;       // 512 d-rows per wave
        constexpr int NIT  = ROWS / 32;     // 16 K-iterations
        const int d0w = wv * ROWS;
        const float* __restrict__ wqb = Wq + (size_t)sa * DI;
        const float* __restrict__ wkb = Wk + (size_t)sa * DI;

        f32x4 accQ = {0.f, 0.f, 0.f, 0.f};
        f32x4 accK = {0.f, 0.f, 0.f, 0.f};

#define P1_LD(IT, A, Q0, Q1, K0, K1) do {                                   \
        const int db_ = d0w + (IT) * 32 + kb * 8;                           \
        const float* __restrict__ hp_ = hbase + (size_t)db_ * DS + sa;      \
        A[0] = hp_[0 * DS]; A[1] = hp_[1 * DS];                             \
        A[2] = hp_[2 * DS]; A[3] = hp_[3 * DS];                             \
        A[4] = hp_[4 * DS]; A[5] = hp_[5 * DS];                             \
        A[6] = hp_[6 * DS]; A[7] = hp_[7 * DS];                             \
        Q0 = *(const float4*)(wqb + db_); Q1 = *(const float4*)(wqb + db_ + 4); \
        K0 = *(const float4*)(wkb + db_); K1 = *(const float4*)(wkb + db_ + 4); \
    } while (0)

#define P1_FMA(A, Q0, Q1, K0, K1) do {                                      \
        bf16x8 af_, bq_, bk_;                                               \
        af_[0] = f2bf(A[0]); af_[1] = f2bf(A[1]);                           \
        af_[2] = f2bf(A[2]); af_[3] = f2bf(A[3]);                           \
        af_[4] = f2bf(A[4]); af_[5] = f2bf(A[5]);                           \
        af_[6] = f2bf(A[6]); af_[7] = f2bf(A[7]);                           \
        bq_[0] = f2bf(Q0.x); bq_[1] = f2bf(Q0.y);                           \
        bq_[2] = f2bf(Q0.z); bq_[3] = f2bf(Q0.w);                           \
        bq_[4] = f2bf(Q1.x); bq_[5] = f2bf(Q1.y);                           \
        bq_[6] = f2bf(Q1.z); bq_[7] = f2bf(Q1.w);                           \
        bk_[0] = f2bf(K0.x); bk_[1] = f2bf(K0.y);                           \
        bk_[2] = f2bf(K0.z); bk_[3] = f2bf(K0.w);                           \
        bk_[4] = f2bf(K1.x); bk_[5] = f2bf(K1.y);                           \
        bk_[6] = f2bf(K1.z); bk_[7] = f2bf(K1.w);                           \
        accQ = __builtin_amdgcn_mfma_f32_16x16x32_bf16(af_, bq_, accQ, 0, 0, 0); \
        accK = __builtin_amdgcn_mfma_f32_16x16x32_bf16(af_, bk_, accK, 0, 0, 0); \
    } while (0)

        float A0[8], A1[8];
        float4 Q00, Q01, K00, K01;
        float4 Q10, Q11, K10, K11;
        P1_LD(0, A0, Q00, Q01, K00, K01);
        P1_LD(1, A1, Q10, Q11, K10, K11);
        for (int it = 0; it < NIT - 2; it += 2) {
            P1_FMA(A0, Q00, Q01, K00, K01);
            P1_LD(it + 2, A0, Q00, Q01, K00, K01);
            P1_FMA(A1, Q10, Q11, K10, K11);
            P1_LD(it + 3, A1, Q10, Q11, K10, K11);
        }
        P1_FMA(A0, Q00, Q01, K00, K01);
        P1_FMA(A1, Q10, Q11, K10, K11);
#undef P1_LD
#undef P1_FMA

        // D mapping (verified): col = lane&15 (=a), row = (lane>>4)*4+reg (=s)
        #pragma unroll
        for (int r = 0; r < 4; ++r) {
            qp[wv][kb * 4 + r][sa] = accQ[r];
            kp[wv][kb * 4 + r][sa] = accK[r];
        }
    }
    __syncthreads();

    // ---------------- reduce the 8 wave partials --------------------------
    {
        const int idx = tid & 255;
        const int s2 = idx >> 4, a2 = idx & 15;
        if (tid < 256) {
            float q = 0.f;
            #pragma unroll
            for (int w = 0; w < NW; ++w) q += qp[w][s2][a2];
            Qs[s2][a2] = q;
        } else {
            float k = 0.f;
            #pragma unroll
            for (int w = 0; w < NW; ++w) k += kp[w][s2][a2];
            Ks[s2][a2] = k;
        }
    }
    __syncthreads();

    // ---------------- Phase 2: scores + softmax + fold gate ---------------
    const float g = gate[0];
    if (tid < 256) {
        const int ss = tid >> 4;   // query slot
        const int tt = tid & 15;   // key slot
        float sc = 0.f;
        #pragma unroll
        for (int a4 = 0; a4 < 16; a4 += 4) {
            float4 qv = *(const float4*)&Qs[ss][a4];
            float4 kv = *(const float4*)&Ks[tt][a4];
            sc = fmaf(qv.x, kv.x, sc);
            sc = fmaf(qv.y, kv.y, sc);
            sc = fmaf(qv.z, kv.z, sc);
            sc = fmaf(qv.w, kv.w, sc);
        }
        sc *= 0.25f;  // D_ATTN^-0.5

        float m = sc;
        #pragma unroll
        for (int o = 8; o > 0; o >>= 1) m = fmaxf(m, __shfl_xor(m, o, 16));
        float e = __expf(sc - m);
        float sm = e;
        #pragma unroll
        for (int o = 8; o > 0; o >>= 1) sm += __shfl_xor(sm, o, 16);
        Ms[ss][tt] = g * (e / sm);
    }
    __syncthreads();

    // ---------------- Phase 3: PV via MFMA + LDS transpose + f4 stores ----
    {
        constexpr int ROWS = DI / NW;       // 512 rows per wave
        constexpr int NT3  = ROWS / 16;     // 32 tiles per wave
        const int rbase = wv * ROWS;
        const int c = sa;                   // MFMA output column (s)
        const int row  = lane >> 2;         // store row within tile
        const int quad = lane & 3;          // store quad within row

        // hoisted B fragment: B[k=t][col=s] = Ms[s][t], zero for t>=16
        bf16x8 bfrag = {0, 0, 0, 0, 0, 0, 0, 0};
        if (kb < 2) {
            const float* mp = &Ms[c][kb * 8];
            float4 m0 = *(const float4*)mp;
            float4 m1 = *(const float4*)(mp + 4);
            bfrag[0] = f2bf(m0.x); bfrag[1] = f2bf(m0.y);
            bfrag[2] = f2bf(m0.z); bfrag[3] = f2bf(m0.w);
            bfrag[4] = f2bf(m1.x); bfrag[5] = f2bf(m1.y);
            bfrag[6] = f2bf(m1.z); bfrag[7] = f2bf(m1.w);
        }

        // A-frag prefetch (kb<2 lanes only; kb>=2 carry K-padding zeros)
        float4 a0n = {0.f, 0.f, 0.f, 0.f}, a1n = {0.f, 0.f, 0.f, 0.f};
        if (kb < 2) {
            const float* hr = hbase + (size_t)(rbase + c) * DS + kb * 8;
            a0n = *(const float4*)hr;
            a1n = *(const float4*)(hr + 4);
        }

        for (int it = 0; it < NT3; ++it) {
            float4 a0 = a0n, a1 = a1n;
            if (it + 1 < NT3 && kb < 2) {
                const float* hr = hbase + (size_t)(rbase + (it + 1) * 16 + c) * DS + kb * 8;
                a0n = *(const float4*)hr;
                a1n = *(const float4*)(hr + 4);
            }

            bf16x8 af;
            af[0] = f2bf(a0.x); af[1] = f2bf(a0.y); af[2] = f2bf(a0.z); af[3] = f2bf(a0.w);
            af[4] = f2bf(a1.x); af[5] = f2bf(a1.y); af[6] = f2bf(a1.z); af[7] = f2bf(a1.w);

            f32x4 acc = {0.f, 0.f, 0.f, 0.f};
            acc = __builtin_amdgcn_mfma_f32_16x16x32_bf16(af, bfrag, acc, 0, 0, 0);

            // transpose D (lane-scalar, col c, rows kb*4+r) -> row-major
            #pragma unroll
            for (int r = 0; r < 4; ++r)
                tr[wv][kb * 4 + r][c] = acc[r];
            __builtin_amdgcn_wave_barrier();   // wave-private tile; order only

            float4 pv = *(const float4*)&tr[wv][row][quad * 4];
            const size_t orow = (size_t)(rbase + it * 16 + row) * DS + quad * 4;
            float4 hres = *(const float4*)(hbase + orow);   // L1-hot (A-frag just read it)
            f32x4 o;
            o[0] = hres.x + pv.x;
            o[1] = hres.y + pv.y;
            o[2] = hres.z + pv.z;
            o[3] = hres.w + pv.w;
            __builtin_nontemporal_store(o, (f32x4*)(obase + orow));
            __builtin_amdgcn_wave_barrier();   // keep next iter's tr writes after reads
        }
    }
}

extern "C" void kernel_launch(void* const* d_in, const int* in_sizes, int n_in,
                              void* d_out, int out_size, void* d_ws, size_t ws_size,
                              hipStream_t stream) {
    const float* h    = (const float*)d_in[0];
    const float* Wq   = (const float*)d_in[1];
    const float* Wk   = (const float*)d_in[2];
    const float* gate = (const float*)d_in[3];
    float* out = (float*)d_out;
    (void)in_sizes; (void)n_in; (void)out_size; (void)d_ws; (void)ws_size;

    ica_fused<<<1024, 512, 0, stream>>>(h, Wq, Wk, gate, out);
}

// Round 8
// 164.716 us; speedup vs baseline: 1.6991x; 1.6199x over previous
//
#include <hip/hip_runtime.h>
#include <hip/hip_bf16.h>

// IntraCellularAttention: B=1024, D_INNER=4096, D_STATE=16, D_ATTN=16
// out[b,d,s] = h[b,d,s] + gate * sum_t attn[b,s,t] * h[b,d,t]
// attn[s,t] = softmax_t( (Q K^T)[s,t] * 0.25 ),  Q[s,a] = sum_d h[b,d,s] Wq[a,d]
//
// Single fused kernel, 512 threads (8 waves), 1 block/batch, grid 1024.
// Target: 4 blocks/CU x 8 waves = 32 waves/CU. VGPR must land <=64 with NO
// spills (round 6/7 lesson: launch_bounds(512,8) forced VGPR=32 -> scratch
// spills -> +370MB HBM traffic). Hence launch_bounds(512,4) + slim state:
// one float landing slot + one bf16 compute slot per phase.
//   Phase 1: Q,K via mfma_16x16x32_bf16; wave covers 512 d-rows.
//   Phase 2: softmax on 256 threads, fold gate into Ms.
//   Phase 3: PV via MFMA (hoisted Ms B-frag, K=16 zero-padded), per-wave LDS
//            transpose (aliasing qp) -> row-major float4 NT stores,
//            fp32 residual from L1-hot re-read.

constexpr int DI = 4096;
constexpr int DS = 16;
constexpr int NW = 8;                       // waves per block

typedef __attribute__((ext_vector_type(8))) short bf16x8;
typedef __attribute__((ext_vector_type(4))) float f32x4;

static __device__ __forceinline__ short f2bf(float x) {
    union { __hip_bfloat16 h; short s; } u;
    u.h = __float2bfloat16(x);
    return u.s;
}

__global__ __launch_bounds__(512, 4) void ica_fused(
    const float* __restrict__ h,
    const float* __restrict__ Wq,
    const float* __restrict__ Wk,
    const float* __restrict__ gate,
    float* __restrict__ out)
{
    const int b    = blockIdx.x;
    const int tid  = threadIdx.x;
    const int lane = tid & 63;
    const int wv   = tid >> 6;              // 0..7

    const float* __restrict__ hbase = h   + (size_t)b * (DI * DS);
    float*       __restrict__ obase = out + (size_t)b * (DI * DS);

    __shared__ float qp[NW][16][17];        // phase1: Q partials; phase3: tr tile
    __shared__ float kp[NW][16][17];        // phase1: K partials
    __shared__ float Qs[16][20];            // reduced Q [s][a]
    __shared__ float Ks[16][20];
    __shared__ float Ms[16][20];            // Ms[s][t] = g * attn[s][t]

    const int sa = lane & 15;               // A row (s) / B row (a) / col
    const int kb = lane >> 4;               // k-subblock 0..3

    // ---------------- Phase 1: Q,K partials via MFMA ----------------------
    // One float landing slot (24 VGPR) + one bf16 slot (12 VGPR): convert as
    // soon as loads land, issue next tile's loads, then MFMA on bf16 regs.
    {
        constexpr int ROWS = DI / NW;       // 512 d-rows per wave
        constexpr int NIT  = ROWS / 32;     // 16 K-iterations
        const int d0w = wv * ROWS;
        const float* __restrict__ wqb = Wq + (size_t)sa * DI;
        const float* __restrict__ wkb = Wk + (size_t)sa * DI;

        f32x4 accQ = {0.f, 0.f, 0.f, 0.f};
        f32x4 accK = {0.f, 0.f, 0.f, 0.f};

        float  F[8];                        // h landing
        float4 FQ0, FQ1, FK0, FK1;          // W landing
        bf16x8 afr, bqr, bkr;               // compute slot

#define P1_LDF(IT) do {                                                     \
        const int db_ = d0w + (IT) * 32 + kb * 8;                           \
        const float* __restrict__ hp_ = hbase + (size_t)db_ * DS + sa;      \
        F[0] = hp_[0 * DS]; F[1] = hp_[1 * DS];                             \
        F[2] = hp_[2 * DS]; F[3] = hp_[3 * DS];                             \
        F[4] = hp_[4 * DS]; F[5] = hp_[5 * DS];                             \
        F[6] = hp_[6 * DS]; F[7] = hp_[7 * DS];                             \
        FQ0 = *(const float4*)(wqb + db_); FQ1 = *(const float4*)(wqb + db_ + 4); \
        FK0 = *(const float4*)(wkb + db_); FK1 = *(const float4*)(wkb + db_ + 4); \
    } while (0)

#define P1_CVT() do {                                                       \
        afr[0] = f2bf(F[0]); afr[1] = f2bf(F[1]);                           \
        afr[2] = f2bf(F[2]); afr[3] = f2bf(F[3]);                           \
        afr[4] = f2bf(F[4]); afr[5] = f2bf(F[5]);                           \
        afr[6] = f2bf(F[6]); afr[7] = f2bf(F[7]);                           \
        bqr[0] = f2bf(FQ0.x); bqr[1] = f2bf(FQ0.y);                         \
        bqr[2] = f2bf(FQ0.z); bqr[3] = f2bf(FQ0.w);                         \
        bqr[4] = f2bf(FQ1.x); bqr[5] = f2bf(FQ1.y);                         \
        bqr[6] = f2bf(FQ1.z); bqr[7] = f2bf(FQ1.w);                         \
        bkr[0] = f2bf(FK0.x); bkr[1] = f2bf(FK0.y);                         \
        bkr[2] = f2bf(FK0.z); bkr[3] = f2bf(FK0.w);                         \
        bkr[4] = f2bf(FK1.x); bkr[5] = f2bf(FK1.y);                         \
        bkr[6] = f2bf(FK1.z); bkr[7] = f2bf(FK1.w);                         \
    } while (0)

        P1_LDF(0);
        for (int it = 0; it < NIT - 1; ++it) {
            P1_CVT();                        // waits on slot's loads
            P1_LDF(it + 1);                  // issue next tile's loads
            accQ = __builtin_amdgcn_mfma_f32_16x16x32_bf16(afr, bqr, accQ, 0, 0, 0);
            accK = __builtin_amdgcn_mfma_f32_16x16x32_bf16(afr, bkr, accK, 0, 0, 0);
        }
        P1_CVT();
        accQ = __builtin_amdgcn_mfma_f32_16x16x32_bf16(afr, bqr, accQ, 0, 0, 0);
        accK = __builtin_amdgcn_mfma_f32_16x16x32_bf16(afr, bkr, accK, 0, 0, 0);
#undef P1_LDF
#undef P1_CVT

        // D mapping (verified): col = lane&15 (=a), row = (lane>>4)*4+reg (=s)
        #pragma unroll
        for (int r = 0; r < 4; ++r) {
            qp[wv][kb * 4 + r][sa] = accQ[r];
            kp[wv][kb * 4 + r][sa] = accK[r];
        }
    }
    __syncthreads();

    // ---------------- reduce the 8 wave partials --------------------------
    {
        const int idx = tid & 255;
        const int s2 = idx >> 4, a2 = idx & 15;
        if (tid < 256) {
            float q = 0.f;
            #pragma unroll
            for (int w = 0; w < NW; ++w) q += qp[w][s2][a2];
            Qs[s2][a2] = q;
        } else {
            float k = 0.f;
            #pragma unroll
            for (int w = 0; w < NW; ++w) k += kp[w][s2][a2];
            Ks[s2][a2] = k;
        }
    }
    __syncthreads();

    // ---------------- Phase 2: scores + softmax + fold gate ---------------
    const float g = gate[0];
    if (tid < 256) {
        const int ss = tid >> 4;   // query slot
        const int tt = tid & 15;   // key slot
        float sc = 0.f;
        #pragma unroll
        for (int a4 = 0; a4 < 16; a4 += 4) {
            float4 qv = *(const float4*)&Qs[ss][a4];
            float4 kv = *(const float4*)&Ks[tt][a4];
            sc = fmaf(qv.x, kv.x, sc);
            sc = fmaf(qv.y, kv.y, sc);
            sc = fmaf(qv.z, kv.z, sc);
            sc = fmaf(qv.w, kv.w, sc);
        }
        sc *= 0.25f;  // D_ATTN^-0.5

        float m = sc;
        #pragma unroll
        for (int o = 8; o > 0; o >>= 1) m = fmaxf(m, __shfl_xor(m, o, 16));
        float e = __expf(sc - m);
        float sm = e;
        #pragma unroll
        for (int o = 8; o > 0; o >>= 1) sm += __shfl_xor(sm, o, 16);
        Ms[ss][tt] = g * (e / sm);
    }
    __syncthreads();
    // qp[][][] is dead from here on -> reused as the phase-3 transpose tile.

    // ---------------- Phase 3: PV via MFMA + LDS transpose + f4 stores ----
    {
        constexpr int ROWS = DI / NW;       // 512 rows per wave
        constexpr int NT3  = ROWS / 16;     // 32 tiles per wave
        const int rbase = wv * ROWS;
        const int c = sa;                   // MFMA output column (s)
        const int row  = lane >> 2;         // store row within tile
        const int quad = lane & 3;          // store quad within row

        // hoisted B fragment: B[k=t][col=s] = Ms[s][t], zero for t>=16
        bf16x8 bfrag = {0, 0, 0, 0, 0, 0, 0, 0};
        if (kb < 2) {
            const float* mp = &Ms[c][kb * 8];
            float4 m0 = *(const float4*)mp;
            float4 m1 = *(const float4*)(mp + 4);
            bfrag[0] = f2bf(m0.x); bfrag[1] = f2bf(m0.y);
            bfrag[2] = f2bf(m0.z); bfrag[3] = f2bf(m0.w);
            bfrag[4] = f2bf(m1.x); bfrag[5] = f2bf(m1.y);
            bfrag[6] = f2bf(m1.z); bfrag[7] = f2bf(m1.w);
        }

        // A landing slot (kb<2 lanes; kb>=2 carry K-padding zeros)
        float4 a0n = {0.f, 0.f, 0.f, 0.f}, a1n = {0.f, 0.f, 0.f, 0.f};
        if (kb < 2) {
            const float* hr = hbase + (size_t)(rbase + c) * DS + kb * 8;
            a0n = *(const float4*)hr;
            a1n = *(const float4*)(hr + 4);
        }

        for (int it = 0; it < NT3; ++it) {
            bf16x8 af;
            af[0] = f2bf(a0n.x); af[1] = f2bf(a0n.y);
            af[2] = f2bf(a0n.z); af[3] = f2bf(a0n.w);
            af[4] = f2bf(a1n.x); af[5] = f2bf(a1n.y);
            af[6] = f2bf(a1n.z); af[7] = f2bf(a1n.w);
            if (it + 1 < NT3 && kb < 2) {
                const float* hr = hbase + (size_t)(rbase + (it + 1) * 16 + c) * DS + kb * 8;
                a0n = *(const float4*)hr;
                a1n = *(const float4*)(hr + 4);
            }

            f32x4 acc = {0.f, 0.f, 0.f, 0.f};
            acc = __builtin_amdgcn_mfma_f32_16x16x32_bf16(af, bfrag, acc, 0, 0, 0);

            // transpose D (lane-scalar, col c, rows kb*4+r) -> row-major
            #pragma unroll
            for (int r = 0; r < 4; ++r)
                qp[wv][kb * 4 + r][c] = acc[r];
            __builtin_amdgcn_wave_barrier();   // wave-private tile; order only

            float4 pv = *(const float4*)&qp[wv][row][quad * 4];
            const size_t orow = (size_t)(rbase + it * 16 + row) * DS + quad * 4;
            float4 hres = *(const float4*)(hbase + orow);   // L1-hot
            f32x4 o;
            o[0] = hres.x + pv.x;
            o[1] = hres.y + pv.y;
            o[2] = hres.z + pv.z;
            o[3] = hres.w + pv.w;
            __builtin_nontemporal_store(o, (f32x4*)(obase + orow));
            __builtin_amdgcn_wave_barrier();   // next iter's writes after reads
        }
    }
}

extern "C" void kernel_launch(void* const* d_in, const int* in_sizes, int n_in,
                              void* d_out, int out_size, void* d_ws, size_t ws_size,
                              hipStream_t stream) {
    const float* h    = (const float*)d_in[0];
    const float* Wq   = (const float*)d_in[1];
    const float* Wk   = (const float*)d_in[2];
    const float* gate = (const float*)d_in[3];
    float* out = (float*)d_out;
    (void)in_sizes; (void)n_in; (void)out_size; (void)d_ws; (void)ws_size;

    ica_fused<<<1024, 512, 0, stream>>>(h, Wq, Wk, gate, out);
}

// Round 9
// 144.899 us; speedup vs baseline: 1.9315x; 1.1368x over previous
//
#include <hip/hip_runtime.h>
#include <hip/hip_bf16.h>

// IntraCellularAttention: B=1024, D_INNER=4096, D_STATE=16, D_ATTN=16
// out[b,d,s] = h[b,d,s] + gate * sum_t attn[b,s,t] * h[b,d,t]
// attn[s,t] = softmax_t( (Q K^T)[s,t] * 0.25 ),  Q[s,a] = sum_d h[b,d,s] Wq[a,d]
//
// 512 threads (8 waves), 1 block/batch, grid 1024, launch_bounds(512,4)
// (round 7 lesson: (512,8) caps VGPR at 32 -> scratch spills -> 2x traffic).
//   Phase 1: Q,K via mfma_16x16x32_bf16; wave covers 512 d-rows; 1 slot.
//   Phase 2: softmax on 256 threads, fold gate into Ms.
//   Phase 3: per 16x16 tile: ONE coalesced float4 load (1KB/inst) -> LDS
//            tile; A-frag via ds_read_b128; MFMA (hoisted Ms B-frag);
//            transpose D back through the same tile; residual added from
//            registers; coalesced float4 NT store. 2 global inst/tile, both
//            100% efficient (round 8 lesson: 256B/inst loads pin BW at 50%).

constexpr int DI = 4096;
constexpr int DS = 16;
constexpr int NW = 8;                       // waves per block

typedef __attribute__((ext_vector_type(8))) short bf16x8;
typedef __attribute__((ext_vector_type(4))) float f32x4;

static __device__ __forceinline__ short f2bf(float x) {
    union { __hip_bfloat16 h; short s; } u;
    u.h = __float2bfloat16(x);
    return u.s;
}

__global__ __launch_bounds__(512, 4) void ica_fused(
    const float* __restrict__ h,
    const float* __restrict__ Wq,
    const float* __restrict__ Wk,
    const float* __restrict__ gate,
    float* __restrict__ out)
{
    const int b    = blockIdx.x;
    const int tid  = threadIdx.x;
    const int lane = tid & 63;
    const int wv   = tid >> 6;              // 0..7

    const float* __restrict__ hbase = h   + (size_t)b * (DI * DS);
    float*       __restrict__ obase = out + (size_t)b * (DI * DS);

    __shared__ float qp[NW][16][20];        // phase1: Q partials; phase3: tile
    __shared__ float kp[NW][16][20];        // phase1: K partials
    __shared__ float Qs[16][20];            // reduced Q [s][a]
    __shared__ float Ks[16][20];
    __shared__ float Ms[16][20];            // Ms[s][t] = g * attn[s][t]

    const int sa = lane & 15;               // A row (s) / B row (a) / col
    const int kb = lane >> 4;               // k-subblock 0..3

    // ---------------- Phase 1: Q,K partials via MFMA ----------------------
    {
        constexpr int ROWS = DI / NW;       // 512 d-rows per wave
        constexpr int NIT  = ROWS / 32;     // 16 K-iterations
        const int d0w = wv * ROWS;
        const float* __restrict__ wqb = Wq + (size_t)sa * DI;
        const float* __restrict__ wkb = Wk + (size_t)sa * DI;

        f32x4 accQ = {0.f, 0.f, 0.f, 0.f};
        f32x4 accK = {0.f, 0.f, 0.f, 0.f};

        float  F[8];                        // h landing
        float4 FQ0, FQ1, FK0, FK1;          // W landing
        bf16x8 afr, bqr, bkr;               // compute slot

#define P1_LDF(IT) do {                                                     \
        const int db_ = d0w + (IT) * 32 + kb * 8;                           \
        const float* __restrict__ hp_ = hbase + (size_t)db_ * DS + sa;      \
        F[0] = hp_[0 * DS]; F[1] = hp_[1 * DS];                             \
        F[2] = hp_[2 * DS]; F[3] = hp_[3 * DS];                             \
        F[4] = hp_[4 * DS]; F[5] = hp_[5 * DS];                             \
        F[6] = hp_[6 * DS]; F[7] = hp_[7 * DS];                             \
        FQ0 = *(const float4*)(wqb + db_); FQ1 = *(const float4*)(wqb + db_ + 4); \
        FK0 = *(const float4*)(wkb + db_); FK1 = *(const float4*)(wkb + db_ + 4); \
    } while (0)

#define P1_CVT() do {                                                       \
        afr[0] = f2bf(F[0]); afr[1] = f2bf(F[1]);                           \
        afr[2] = f2bf(F[2]); afr[3] = f2bf(F[3]);                           \
        afr[4] = f2bf(F[4]); afr[5] = f2bf(F[5]);                           \
        afr[6] = f2bf(F[6]); afr[7] = f2bf(F[7]);                           \
        bqr[0] = f2bf(FQ0.x); bqr[1] = f2bf(FQ0.y);                         \
        bqr[2] = f2bf(FQ0.z); bqr[3] = f2bf(FQ0.w);                         \
        bqr[4] = f2bf(FQ1.x); bqr[5] = f2bf(FQ1.y);                         \
        bqr[6] = f2bf(FQ1.z); bqr[7] = f2bf(FQ1.w);                         \
        bkr[0] = f2bf(FK0.x); bkr[1] = f2bf(FK0.y);                         \
        bkr[2] = f2bf(FK0.z); bkr[3] = f2bf(FK0.w);                         \
        bkr[4] = f2bf(FK1.x); bkr[5] = f2bf(FK1.y);                         \
        bkr[6] = f2bf(FK1.z); bkr[7] = f2bf(FK1.w);                         \
    } while (0)

        P1_LDF(0);
        for (int it = 0; it < NIT - 1; ++it) {
            P1_CVT();
            P1_LDF(it + 1);
            accQ = __builtin_amdgcn_mfma_f32_16x16x32_bf16(afr, bqr, accQ, 0, 0, 0);
            accK = __builtin_amdgcn_mfma_f32_16x16x32_bf16(afr, bkr, accK, 0, 0, 0);
        }
        P1_CVT();
        accQ = __builtin_amdgcn_mfma_f32_16x16x32_bf16(afr, bqr, accQ, 0, 0, 0);
        accK = __builtin_amdgcn_mfma_f32_16x16x32_bf16(afr, bkr, accK, 0, 0, 0);
#undef P1_LDF
#undef P1_CVT

        // D mapping (verified): col = lane&15 (=a), row = (lane>>4)*4+reg (=s)
        #pragma unroll
        for (int r = 0; r < 4; ++r) {
            qp[wv][kb * 4 + r][sa] = accQ[r];
            kp[wv][kb * 4 + r][sa] = accK[r];
        }
    }
    __syncthreads();

    // ---------------- reduce the 8 wave partials --------------------------
    {
        const int idx = tid & 255;
        const int s2 = idx >> 4, a2 = idx & 15;
        if (tid < 256) {
            float q = 0.f;
            #pragma unroll
            for (int w = 0; w < NW; ++w) q += qp[w][s2][a2];
            Qs[s2][a2] = q;
        } else {
            float k = 0.f;
            #pragma unroll
            for (int w = 0; w < NW; ++w) k += kp[w][s2][a2];
            Ks[s2][a2] = k;
        }
    }
    __syncthreads();

    // ---------------- Phase 2: scores + softmax + fold gate ---------------
    const float g = gate[0];
    if (tid < 256) {
        const int ss = tid >> 4;   // query slot
        const int tt = tid & 15;   // key slot
        float sc = 0.f;
        #pragma unroll
        for (int a4 = 0; a4 < 16; a4 += 4) {
            float4 qv = *(const float4*)&Qs[ss][a4];
            float4 kv = *(const float4*)&Ks[tt][a4];
            sc = fmaf(qv.x, kv.x, sc);
            sc = fmaf(qv.y, kv.y, sc);
            sc = fmaf(qv.z, kv.z, sc);
            sc = fmaf(qv.w, kv.w, sc);
        }
        sc *= 0.25f;  // D_ATTN^-0.5

        float m = sc;
        #pragma unroll
        for (int o = 8; o > 0; o >>= 1) m = fmaxf(m, __shfl_xor(m, o, 16));
        float e = __expf(sc - m);
        float sm = e;
        #pragma unroll
        for (int o = 8; o > 0; o >>= 1) sm += __shfl_xor(sm, o, 16);
        Ms[ss][tt] = g * (e / sm);
    }
    __syncthreads();
    // qp is dead from here -> reused as the per-wave phase-3 tile.

    // ---------------- Phase 3: single-load tile PV ------------------------
    {
        constexpr int ROWS = DI / NW;       // 512 rows per wave
        constexpr int NT3  = ROWS / 16;     // 32 tiles per wave
        const int rbase = wv * ROWS;
        const int row  = lane >> 2;         // tile row this lane stages/stores
        const int quad = lane & 3;          // float4 slot within the row

        float (* __restrict__ st)[20] = qp[wv];   // per-wave 16x20 tile

        // hoisted B fragment: B[k=t][col=s] = Ms[s][t], zero for t>=16
        bf16x8 bfrag = {0, 0, 0, 0, 0, 0, 0, 0};
        if (kb < 2) {
            const float* mp = &Ms[sa][kb * 8];
            float4 m0 = *(const float4*)mp;
            float4 m1 = *(const float4*)(mp + 4);
            bfrag[0] = f2bf(m0.x); bfrag[1] = f2bf(m0.y);
            bfrag[2] = f2bf(m0.z); bfrag[3] = f2bf(m0.w);
            bfrag[4] = f2bf(m1.x); bfrag[5] = f2bf(m1.y);
            bfrag[6] = f2bf(m1.z); bfrag[7] = f2bf(m1.w);
        }

        // prefetch tile 0 (fully coalesced: 64 lanes x 16B = the whole 1KB tile)
        float4 hn = *(const float4*)(hbase + (size_t)(rbase + row) * DS + quad * 4);

        for (int it = 0; it < NT3; ++it) {
            const float4 hres = hn;
            // stage tile into LDS (b128, <=2-way banks)
            *(float4*)&st[row][quad * 4] = hres;
            if (it + 1 < NT3)
                hn = *(const float4*)(hbase + (size_t)(rbase + (it + 1) * 16 + row) * DS + quad * 4);
            __builtin_amdgcn_wave_barrier();

            // A-frag from LDS: lane (sa,kb) needs tile[sa][kb*8..+8]; kb>=2 -> 0
            const float* ap = &st[sa][(kb & 1) * 8];
            float4 aa0 = *(const float4*)ap;
            float4 aa1 = *(const float4*)(ap + 4);
            if (kb >= 2) {
                aa0 = make_float4(0.f, 0.f, 0.f, 0.f);
                aa1 = make_float4(0.f, 0.f, 0.f, 0.f);
            }
            bf16x8 af;
            af[0] = f2bf(aa0.x); af[1] = f2bf(aa0.y);
            af[2] = f2bf(aa0.z); af[3] = f2bf(aa0.w);
            af[4] = f2bf(aa1.x); af[5] = f2bf(aa1.y);
            af[6] = f2bf(aa1.z); af[7] = f2bf(aa1.w);

            f32x4 acc = {0.f, 0.f, 0.f, 0.f};
            acc = __builtin_amdgcn_mfma_f32_16x16x32_bf16(af, bfrag, acc, 0, 0, 0);
            __builtin_amdgcn_wave_barrier();   // all A-frag reads done before overwrite

            // transpose D (lane-scalar: col sa, rows kb*4+r) into the tile
            #pragma unroll
            for (int r = 0; r < 4; ++r)
                st[kb * 4 + r][sa] = acc[r];
            __builtin_amdgcn_wave_barrier();

            float4 pv = *(const float4*)&st[row][quad * 4];
            f32x4 o;
            o[0] = hres.x + pv.x;
            o[1] = hres.y + pv.y;
            o[2] = hres.z + pv.z;
            o[3] = hres.w + pv.w;
            const size_t orow = (size_t)(rbase + it * 16 + row) * DS + quad * 4;
            __builtin_nontemporal_store(o, (f32x4*)(obase + orow));
            __builtin_amdgcn_wave_barrier();   // next iter's staging after pv reads
        }
    }
}

extern "C" void kernel_launch(void* const* d_in, const int* in_sizes, int n_in,
                              void* d_out, int out_size, void* d_ws, size_t ws_size,
                              hipStream_t stream) {
    const float* h    = (const float*)d_in[0];
    const float* Wq   = (const float*)d_in[1];
    const float* Wk   = (const float*)d_in[2];
    const float* gate = (const float*)d_in[3];
    float* out = (float*)d_out;
    (void)in_sizes; (void)n_in; (void)out_size; (void)d_ws; (void)ws_size;

    ica_fused<<<1024, 512, 0, stream>>>(h, Wq, Wk, gate, out);
}

// Round 11
// 115.737 us; speedup vs baseline: 2.4182x; 1.2520x over previous
//
#include <hip/hip_runtime.h>
#include <hip/hip_bf16.h>

// IntraCellularAttention: B=1024, D_INNER=4096, D_STATE=16, D_ATTN=16
// out[b,d,s] = h[b,d,s] + gate * sum_t attn[b,s,t] * h[b,d,t]
// attn[s,t] = softmax_t( (Q K^T)[s,t] * 0.25 ),  Q[s,a] = sum_d h[b,d,s] Wq[a,d]
//
// Register-resident h: 512 threads (8 waves), 1 block/batch, grid 1024.
// Each lane holds 32 float4 of h (128 VGPR) loaded ONCE, fully coalesced
// (1KB/instruction), 3-chunk lookahead. launch_bounds(512,1) -> VGPR cap 256.
// ROUND-10 BUG FIXED: with lookahead distance == slot count (3), the
// prefetch LD_CHUNK(c+3, (c+3)%3) clobbered slot c%3 BEFORE its W values
// were consumed -> B-fragments came from the wrong chunk. Fix: convert the
// slot's W to bf16 (bq,bk) BEFORE issuing the lookahead into that slot.
//   Phase 1: per 32-row chunk: regs -> LDS tile -> col-read A-frag,
//            mfma_16x16x32_bf16 vs W row slices (L2).
//   Phase 2: softmax on 256 threads, fold gate into Ms.
//   Phase 3: ZERO global reads: regs -> LDS -> A-frag, MFMA (hoisted Ms),
//            transpose-back via LDS, residual from registers, NT f4 stores.

constexpr int DI = 4096;
constexpr int DS = 16;
constexpr int NW = 8;                       // waves per block

typedef __attribute__((ext_vector_type(8))) short bf16x8;
typedef __attribute__((ext_vector_type(4))) float f32x4;

static __device__ __forceinline__ short f2bf(float x) {
    union { __hip_bfloat16 h; short s; } u;
    u.h = __float2bfloat16(x);
    return u.s;
}

__global__ __launch_bounds__(512, 1) void ica_fused(
    const float* __restrict__ h,
    const float* __restrict__ Wq,
    const float* __restrict__ Wk,
    const float* __restrict__ gate,
    float* __restrict__ out)
{
    const int b    = blockIdx.x;
    const int tid  = threadIdx.x;
    const int lane = tid & 63;
    const int wv   = tid >> 6;              // 0..7

    const float* __restrict__ hbase = h   + (size_t)b * (DI * DS);
    float*       __restrict__ obase = out + (size_t)b * (DI * DS);

    __shared__ float st[NW][32][20];        // per-wave transpose tile
    __shared__ float qp[NW][16][20];        // Q partials [w][s][a]
    __shared__ float kp[NW][16][20];        // K partials
    __shared__ float Qs[16][20];
    __shared__ float Ks[16][20];
    __shared__ float Ms[16][20];            // Ms[s][t] = g * attn[s][t]

    const int sa   = lane & 15;             // A/B row index and MFMA col
    const int kb   = lane >> 4;             // k-subblock 0..3
    const int row  = lane >> 2;             // coalesced-layout row (0..15)
    const int quad = lane & 3;              // float4 slot within row

    // wave's 512 rows as 2048 float4; lane's j-th f4 = row j*16+row, quad
    const float4* __restrict__ h4 = (const float4*)hbase + (size_t)wv * 2048;
    const int d0w = wv * 512;

    float4 H[32];                           // register-resident h slice

    // ---------------- Phase 1: Q,K via MFMA, regs->LDS transpose ----------
    {
        const float* __restrict__ wqb = Wq + (size_t)sa * DI;
        const float* __restrict__ wkb = Wk + (size_t)sa * DI;

        f32x4 accQ = {0.f, 0.f, 0.f, 0.f};
        f32x4 accK = {0.f, 0.f, 0.f, 0.f};

        float4 WQ0[3], WQ1[3], WK0[3], WK1[3];   // 3-slot W landing (L2)

#define LD_CHUNK(C, SL) do {                                                \
        H[2*(C)]   = h4[(2*(C)) * 64 + lane];                               \
        H[2*(C)+1] = h4[(2*(C)+1) * 64 + lane];                             \
        const int db_ = d0w + (C) * 32 + kb * 8;                            \
        WQ0[SL] = *(const float4*)(wqb + db_);                              \
        WQ1[SL] = *(const float4*)(wqb + db_ + 4);                          \
        WK0[SL] = *(const float4*)(wkb + db_);                              \
        WK1[SL] = *(const float4*)(wkb + db_ + 4);                          \
    } while (0)

        LD_CHUNK(0, 0);
        LD_CHUNK(1, 1);
        LD_CHUNK(2, 2);

        #pragma unroll
        for (int c = 0; c < 16; ++c) {
            const int sl = c % 3;
            // stage chunk c (32 rows) into the wave tile
            *(float4*)&st[wv][row][quad * 4]      = H[2*c];
            *(float4*)&st[wv][row + 16][quad * 4] = H[2*c + 1];

            // consume this slot's W into bf16 regs BEFORE the lookahead
            // overwrites it ((c+3)%3 == c%3 -- the round-10 bug)
            bf16x8 bq, bk;
            bq[0] = f2bf(WQ0[sl].x); bq[1] = f2bf(WQ0[sl].y);
            bq[2] = f2bf(WQ0[sl].z); bq[3] = f2bf(WQ0[sl].w);
            bq[4] = f2bf(WQ1[sl].x); bq[5] = f2bf(WQ1[sl].y);
            bq[6] = f2bf(WQ1[sl].z); bq[7] = f2bf(WQ1[sl].w);
            bk[0] = f2bf(WK0[sl].x); bk[1] = f2bf(WK0[sl].y);
            bk[2] = f2bf(WK0[sl].z); bk[3] = f2bf(WK0[sl].w);
            bk[4] = f2bf(WK1[sl].x); bk[5] = f2bf(WK1[sl].y);
            bk[6] = f2bf(WK1[sl].z); bk[7] = f2bf(WK1[sl].w);

            __builtin_amdgcn_wave_barrier();   // staging done before A reads

            // issue lookahead chunk into the now-free slot
            if (c + 3 < 16) LD_CHUNK(c + 3, sl);

            // A-frag: S[sa][d] = h[d][sa], d = chunk-local kb*8+i
            bf16x8 af;
            #pragma unroll
            for (int i = 0; i < 8; ++i)
                af[i] = f2bf(st[wv][kb * 8 + i][sa]);

            accQ = __builtin_amdgcn_mfma_f32_16x16x32_bf16(af, bq, accQ, 0, 0, 0);
            accK = __builtin_amdgcn_mfma_f32_16x16x32_bf16(af, bk, accK, 0, 0, 0);
            __builtin_amdgcn_wave_barrier();   // tile reads done before re-stage
        }
#undef LD_CHUNK

        // D mapping (verified): col = lane&15 (=a), row = (lane>>4)*4+reg (=s)
        #pragma unroll
        for (int r = 0; r < 4; ++r) {
            qp[wv][kb * 4 + r][sa] = accQ[r];
            kp[wv][kb * 4 + r][sa] = accK[r];
        }
    }
    __syncthreads();

    // ---------------- reduce the 8 wave partials --------------------------
    {
        const int idx = tid & 255;
        const int s2 = idx >> 4, a2 = idx & 15;
        if (tid < 256) {
            float q = 0.f;
            #pragma unroll
            for (int w = 0; w < NW; ++w) q += qp[w][s2][a2];
            Qs[s2][a2] = q;
        } else {
            float k = 0.f;
            #pragma unroll
            for (int w = 0; w < NW; ++w) k += kp[w][s2][a2];
            Ks[s2][a2] = k;
        }
    }
    __syncthreads();

    // ---------------- Phase 2: scores + softmax + fold gate ---------------
    const float g = gate[0];
    if (tid < 256) {
        const int ss = tid >> 4;   // query slot
        const int tt = tid & 15;   // key slot
        float sc = 0.f;
        #pragma unroll
        for (int a4 = 0; a4 < 16; a4 += 4) {
            float4 qv = *(const float4*)&Qs[ss][a4];
            float4 kv = *(const float4*)&Ks[tt][a4];
            sc = fmaf(qv.x, kv.x, sc);
            sc = fmaf(qv.y, kv.y, sc);
            sc = fmaf(qv.z, kv.z, sc);
            sc = fmaf(qv.w, kv.w, sc);
        }
        sc *= 0.25f;  // D_ATTN^-0.5

        float m = sc;
        #pragma unroll
        for (int o = 8; o > 0; o >>= 1) m = fmaxf(m, __shfl_xor(m, o, 16));
        float e = __expf(sc - m);
        float sm = e;
        #pragma unroll
        for (int o = 8; o > 0; o >>= 1) sm += __shfl_xor(sm, o, 16);
        Ms[ss][tt] = g * (e / sm);
    }
    __syncthreads();

    // ---------------- Phase 3: PV from registers, zero global reads -------
    {
        float (* __restrict__ stw)[20] = st[wv];

        // hoisted B fragment: B[k=t][col=s] = Ms[s][t], zero for t>=16
        bf16x8 bfrag = {0, 0, 0, 0, 0, 0, 0, 0};
        if (kb < 2) {
            const float* mp = &Ms[sa][kb * 8];
            float4 m0 = *(const float4*)mp;
            float4 m1 = *(const float4*)(mp + 4);
            bfrag[0] = f2bf(m0.x); bfrag[1] = f2bf(m0.y);
            bfrag[2] = f2bf(m0.z); bfrag[3] = f2bf(m0.w);
            bfrag[4] = f2bf(m1.x); bfrag[5] = f2bf(m1.y);
            bfrag[6] = f2bf(m1.z); bfrag[7] = f2bf(m1.w);
        }

        #pragma unroll
        for (int it = 0; it < 32; ++it) {
            // stage tile from registers
            *(float4*)&stw[row][quad * 4] = H[it];
            __builtin_amdgcn_wave_barrier();

            // A-frag: tile[sa][(kb&1)*8 ..+7]; kb>=2 lanes carry K-padding 0
            const float* ap = &stw[sa][(kb & 1) * 8];
            float4 aa0 = *(const float4*)ap;
            float4 aa1 = *(const float4*)(ap + 4);
            if (kb >= 2) {
                aa0 = make_float4(0.f, 0.f, 0.f, 0.f);
                aa1 = make_float4(0.f, 0.f, 0.f, 0.f);
            }
            bf16x8 af;
            af[0] = f2bf(aa0.x); af[1] = f2bf(aa0.y);
            af[2] = f2bf(aa0.z); af[3] = f2bf(aa0.w);
            af[4] = f2bf(aa1.x); af[5] = f2bf(aa1.y);
            af[6] = f2bf(aa1.z); af[7] = f2bf(aa1.w);

            f32x4 acc = {0.f, 0.f, 0.f, 0.f};
            acc = __builtin_amdgcn_mfma_f32_16x16x32_bf16(af, bfrag, acc, 0, 0, 0);
            __builtin_amdgcn_wave_barrier();   // A reads done before transpose

            // transpose D (col sa, rows kb*4+r) back through the tile
            #pragma unroll
            for (int r = 0; r < 4; ++r)
                stw[kb * 4 + r][sa] = acc[r];
            __builtin_amdgcn_wave_barrier();

            float4 pv = *(const float4*)&stw[row][quad * 4];
            f32x4 o;
            o[0] = H[it].x + pv.x;
            o[1] = H[it].y + pv.y;
            o[2] = H[it].z + pv.z;
            o[3] = H[it].w + pv.w;
            const size_t orow = (size_t)(d0w + it * 16 + row) * DS + quad * 4;
            __builtin_nontemporal_store(o, (f32x4*)(obase + orow));
            __builtin_amdgcn_wave_barrier();   // pv reads done before next stage
        }
    }
}

extern "C" void kernel_launch(void* const* d_in, const int* in_sizes, int n_in,
                              void* d_out, int out_size, void* d_ws, size_t ws_size,
                              hipStream_t stream) {
    const float* h    = (const float*)d_in[0];
    const float* Wq   = (const float*)d_in[1];
    const float* Wk   = (const float*)d_in[2];
    const float* gate = (const float*)d_in[3];
    float* out = (float*)d_out;
    (void)in_sizes; (void)n_in; (void)out_size; (void)d_ws; (void)ws_size;

    ica_fused<<<1024, 512, 0, stream>>>(h, Wq, Wk, gate, out);
}